// Round 10
// baseline (332.234 us; speedup 1.0000x reference)
//
#include <hip/hip_runtime.h>
#include <math.h>

#define NR 36
#define NW 32
#define DD 1024
#define EPSF 1e-8f

typedef _Float16 f16x8 __attribute__((ext_vector_type(8)));
typedef float f32x16 __attribute__((ext_vector_type(16)));
#define MFMA32(a, b, c) __builtin_amdgcn_mfma_f32_32x32x16_f16((a), (b), (c), 0, 0, 0)

__device__ __forceinline__ float leakyf(float x) { return x > 0.f ? x : 0.1f * x; }

// ============ prep: grams (full symmetric) + norms + f16 hi/lo fragment planes ============
// blocks 0..127: image i ; blocks 128..255: caption cb
// Frag layout (f16): X[((mt*128 + kq)*32 + ml)*8 + j], row = mt*32+ml, k = kq*8+j
__global__ __launch_bounds__(256) void prep_kernel(
    const float* __restrict__ img, const float* __restrict__ cap,
    float* __restrict__ Gimg, float* __restrict__ Gcap,
    float* __restrict__ imgn, float* __restrict__ capn,
    _Float16* __restrict__ Ahf, _Float16* __restrict__ Alf,
    _Float16* __restrict__ Bhf, _Float16* __restrict__ Blf) {
  __shared__ float sA[NR][68];
  const int t = threadIdx.x;
  if (blockIdx.x < 128) {
    const int i = blockIdx.x;
    const float* A = img + (size_t)i * NR * DD;
    int ti = 0, tj = 0;
    const bool active = t < 171;  // 18*19/2 upper-tri 2x2 tiles
    if (active) {
      int rem = t, rl = 18;
      while (rem >= rl) { rem -= rl; ++ti; --rl; }
      tj = ti + rem;
    }
    const int a0 = 2 * ti, a1 = 2 * ti + 1, b0 = 2 * tj, b1 = 2 * tj + 1;
    float g00 = 0.f, g01 = 0.f, g10 = 0.f, g11 = 0.f;
    for (int k0 = 0; k0 < DD; k0 += 64) {
      for (int s = t; s < NR * 8; s += 256) {  // 288 tasks: kq8 = s/36, r = s%36
        const int kq8 = s / NR, r = s - kq8 * NR;
        const int kk = k0 + kq8 * 8;
        const float4 v0 = *(const float4*)(A + r * DD + kk);
        const float4 v1 = *(const float4*)(A + r * DD + kk + 4);
        *(float4*)&sA[r][kq8 * 8] = v0;
        *(float4*)&sA[r][kq8 * 8 + 4] = v1;
        const float a[8] = {v0.x, v0.y, v0.z, v0.w, v1.x, v1.y, v1.z, v1.w};
        f16x8 hv, lv;
#pragma unroll
        for (int j = 0; j < 8; ++j) {
          const _Float16 hh = (_Float16)a[j];
          hv[j] = hh;
          lv[j] = (_Float16)(a[j] - (float)hh);
        }
        const int m = i * NR + r, mt = m >> 5, ml = m & 31;
        const size_t fo = (((size_t)mt * 128 + (kk >> 3)) * 32 + ml) * 8;
        *(f16x8*)(Ahf + fo) = hv;
        *(f16x8*)(Alf + fo) = lv;
      }
      __syncthreads();
      if (active) {
#pragma unroll
        for (int k = 0; k < 16; ++k) {
          const float4 va0 = *(const float4*)&sA[a0][k * 4];
          const float4 va1 = *(const float4*)&sA[a1][k * 4];
          const float4 vb0 = *(const float4*)&sA[b0][k * 4];
          const float4 vb1 = *(const float4*)&sA[b1][k * 4];
          g00 = fmaf(va0.x, vb0.x, g00); g00 = fmaf(va0.y, vb0.y, g00);
          g00 = fmaf(va0.z, vb0.z, g00); g00 = fmaf(va0.w, vb0.w, g00);
          g01 = fmaf(va0.x, vb1.x, g01); g01 = fmaf(va0.y, vb1.y, g01);
          g01 = fmaf(va0.z, vb1.z, g01); g01 = fmaf(va0.w, vb1.w, g01);
          g10 = fmaf(va1.x, vb0.x, g10); g10 = fmaf(va1.y, vb0.y, g10);
          g10 = fmaf(va1.z, vb0.z, g10); g10 = fmaf(va1.w, vb0.w, g10);
          g11 = fmaf(va1.x, vb1.x, g11); g11 = fmaf(va1.y, vb1.y, g11);
          g11 = fmaf(va1.z, vb1.z, g11); g11 = fmaf(va1.w, vb1.w, g11);
        }
      }
      __syncthreads();
    }
    if (active) {
      float* Gi = Gimg + (size_t)i * NR * NR;
      Gi[a0 * NR + b0] = g00; Gi[b0 * NR + a0] = g00;
      Gi[a0 * NR + b1] = g01; Gi[b1 * NR + a0] = g01;
      Gi[a1 * NR + b0] = g10; Gi[b0 * NR + a1] = g10;
      Gi[a1 * NR + b1] = g11; Gi[b1 * NR + a1] = g11;
      if (ti == tj) {
        imgn[i * NR + a0] = fmaxf(sqrtf(g00), EPSF);
        imgn[i * NR + a1] = fmaxf(sqrtf(g11), EPSF);
      }
    }
  } else {
    const int cb = blockIdx.x - 128;
    const float* A = cap + (size_t)cb * NW * DD;
    int ti = 0, tj = 0;
    const bool active = t < 136;  // 16*17/2
    if (active) {
      int rem = t, rl = 16;
      while (rem >= rl) { rem -= rl; ++ti; --rl; }
      tj = ti + rem;
    }
    const int a0 = 2 * ti, a1 = 2 * ti + 1, b0 = 2 * tj, b1 = 2 * tj + 1;
    float g00 = 0.f, g01 = 0.f, g10 = 0.f, g11 = 0.f;
    for (int k0 = 0; k0 < DD; k0 += 64) {
      {  // 256 tasks: kq8 = s>>5, r = s&31
        const int s = t;
        const int kq8 = s >> 5, r = s & 31;
        const int kk = k0 + kq8 * 8;
        const float4 v0 = *(const float4*)(A + r * DD + kk);
        const float4 v1 = *(const float4*)(A + r * DD + kk + 4);
        *(float4*)&sA[r][kq8 * 8] = v0;
        *(float4*)&sA[r][kq8 * 8 + 4] = v1;
        const float a[8] = {v0.x, v0.y, v0.z, v0.w, v1.x, v1.y, v1.z, v1.w};
        f16x8 hv, lv;
#pragma unroll
        for (int j = 0; j < 8; ++j) {
          const _Float16 hh = (_Float16)a[j];
          hv[j] = hh;
          lv[j] = (_Float16)(a[j] - (float)hh);
        }
        const size_t fo = (((size_t)cb * 128 + (kk >> 3)) * 32 + r) * 8;
        *(f16x8*)(Bhf + fo) = hv;
        *(f16x8*)(Blf + fo) = lv;
      }
      __syncthreads();
      if (active) {
#pragma unroll
        for (int k = 0; k < 16; ++k) {
          const float4 va0 = *(const float4*)&sA[a0][k * 4];
          const float4 va1 = *(const float4*)&sA[a1][k * 4];
          const float4 vb0 = *(const float4*)&sA[b0][k * 4];
          const float4 vb1 = *(const float4*)&sA[b1][k * 4];
          g00 = fmaf(va0.x, vb0.x, g00); g00 = fmaf(va0.y, vb0.y, g00);
          g00 = fmaf(va0.z, vb0.z, g00); g00 = fmaf(va0.w, vb0.w, g00);
          g01 = fmaf(va0.x, vb1.x, g01); g01 = fmaf(va0.y, vb1.y, g01);
          g01 = fmaf(va0.z, vb1.z, g01); g01 = fmaf(va0.w, vb1.w, g01);
          g10 = fmaf(va1.x, vb0.x, g10); g10 = fmaf(va1.y, vb0.y, g10);
          g10 = fmaf(va1.z, vb0.z, g10); g10 = fmaf(va1.w, vb0.w, g10);
          g11 = fmaf(va1.x, vb1.x, g11); g11 = fmaf(va1.y, vb1.y, g11);
          g11 = fmaf(va1.z, vb1.z, g11); g11 = fmaf(va1.w, vb1.w, g11);
        }
      }
      __syncthreads();
    }
    if (active) {
      float* Gc = Gcap + (size_t)cb * NW * NW;
      Gc[a0 * NW + b0] = g00; Gc[b0 * NW + a0] = g00;
      Gc[a0 * NW + b1] = g01; Gc[b1 * NW + a0] = g01;
      Gc[a1 * NW + b0] = g10; Gc[b0 * NW + a1] = g10;
      Gc[a1 * NW + b1] = g11; Gc[b1 * NW + a1] = g11;
      if (ti == tj) {
        capn[cb * NW + a0] = fmaxf(sqrtf(g00), EPSF);
        capn[cb * NW + a1] = fmaxf(sqrtf(g11), EPSF);
      }
    }
  }
}

// ============ MFMA GEMM v3: BARRIER-FREE. All fragments direct global->VGPR, dbuf ========
// No LDS, no __syncthreads in K-loop -> compiler emits fine-grained vmcnt(N) pipelining.
// 256 thr / 4 waves; each wave an independent 64x64 tile (2 m-tiles x 2 n-tiles).
// Grid 1152, XCD-pinned: yb from bid&7 so each XCD's 4 B-slices (2 MB) stay L2-resident.
__global__ __launch_bounds__(256, 2) void mfma_gemm_kernel(
    const _Float16* __restrict__ Ahf, const _Float16* __restrict__ Alf,
    const _Float16* __restrict__ Bhf, const _Float16* __restrict__ Blf, float* __restrict__ C) {
  const int bid = blockIdx.x;
  const int xb = bid >> 5;
  const int yb = (bid & 7) * 4 + ((bid >> 3) & 3);
  const int tid = threadIdx.x;
  const int wv = tid >> 6, lane = tid & 63;
  const int lm = lane & 31, kb = lane >> 5;
  const int Mt0 = xb * 4 + (wv >> 1) * 2;  // this wave's 2 m-tiles
  const int Nt0 = yb * 4 + (wv & 1) * 2;   // this wave's 2 n-tiles (caption tiles)
  // element offsets (halves): X[(tile*128 + kt*4 + ks*2 + kb)*256 + lm*8], plane via base ptr
  const size_t aoff = ((size_t)Mt0 * 128 + kb) * 256 + (size_t)lm * 8;
  const size_t boff = ((size_t)Nt0 * 128 + kb) * 256 + (size_t)lm * 8;
  const size_t TS = 128 * 256;  // tile stride (halves)
  const size_t KS = 2 * 256;    // ks stride
  const size_t KT = 4 * 256;    // kt stride

  f32x16 acc[2][2];
#pragma unroll
  for (int a = 0; a < 2; ++a)
#pragma unroll
    for (int b = 0; b < 2; ++b) acc[a][b] = {};
  f16x8 a0[2][2][2], a1[2][2][2], b0[2][2][2], b1[2][2][2];

  auto loadAB = [&](int kt, f16x8 af[2][2][2], f16x8 bf[2][2][2]) {
    const size_t ak = aoff + (size_t)kt * KT;
    const size_t bk = boff + (size_t)kt * KT;
#pragma unroll
    for (int tt = 0; tt < 2; ++tt)
#pragma unroll
      for (int ks = 0; ks < 2; ++ks) {
        const size_t oa = ak + tt * TS + ks * KS;
        af[tt][ks][0] = *(const f16x8*)(Ahf + oa);
        af[tt][ks][1] = *(const f16x8*)(Alf + oa);
        const size_t ob = bk + tt * TS + ks * KS;
        bf[tt][ks][0] = *(const f16x8*)(Bhf + ob);
        bf[tt][ks][1] = *(const f16x8*)(Blf + ob);
      }
  };
  auto compute = [&](const f16x8 af[2][2][2], const f16x8 bf[2][2][2]) {
#pragma unroll
    for (int ks = 0; ks < 2; ++ks)
#pragma unroll
      for (int nt = 0; nt < 2; ++nt) {
        const f16x8 bh = bf[nt][ks][0];
        const f16x8 bl = bf[nt][ks][1];
        acc[0][nt] = MFMA32(af[0][ks][0], bh, acc[0][nt]);
        acc[1][nt] = MFMA32(af[1][ks][0], bh, acc[1][nt]);
        acc[0][nt] = MFMA32(af[0][ks][1], bh, acc[0][nt]);
        acc[1][nt] = MFMA32(af[1][ks][1], bh, acc[1][nt]);
        acc[0][nt] = MFMA32(af[0][ks][0], bl, acc[0][nt]);
        acc[1][nt] = MFMA32(af[1][ks][0], bl, acc[1][nt]);
      }
  };

  loadAB(0, a0, b0);
  for (int kt2 = 0; kt2 < 16; ++kt2) {
    const int kt = kt2 * 2;
    if (kt + 1 < 32) loadAB(kt + 1, a1, b1);
    compute(a0, b0);
    if (kt + 2 < 32) loadAB(kt + 2, a0, b0);
    compute(a1, b1);
  }
  // epilogue: C/D layout col=lane&31, row=(q&3)+8*(q>>2)+4*kb ; C[((il*128+c)*36+r)*32+w]
#pragma unroll
  for (int mt = 0; mt < 2; ++mt)
#pragma unroll
    for (int ntl = 0; ntl < 2; ++ntl) {
      const int cc = Nt0 + ntl;  // n-tile == caption index (32 words per caption)
      const f32x16 a = acc[mt][ntl];
#pragma unroll
      for (int q = 0; q < 16; ++q) {
        const int row32 = (q & 3) + 8 * (q >> 2) + 4 * kb;
        const int m = (Mt0 + mt) * 32 + row32;
        const int il = m / NR, r = m - il * NR;
        C[((size_t)il * 128 + cc) * (NR * NW) + r * NW + lm] = a[q];
      }
    }
}

// ============ fused post-GEMM: S in LDS (stride 36), G via wave-uniform s_load ============
__global__ __launch_bounds__(256) void fused_attn_kernel(
    const float* __restrict__ C, const float* __restrict__ Gimg, const float* __restrict__ Gcap,
    const float* __restrict__ imgn, const float* __restrict__ capn, float* __restrict__ out) {
  const int i = blockIdx.x;
  const int cg = blockIdx.y;
  const int tid = threadIdx.x;
  const int wv = tid >> 6, lane = tid & 63;
  __shared__ float sS[8][NR * 36];
  __shared__ float sInvR[8][NR];
  __shared__ float sInvC[8][NW];
  __shared__ float red[8];
  if (tid < 8) red[tid] = 0.f;
  const float* Cp = C + ((size_t)i * 128 + cg * 8) * (NR * NW);
  for (int t = tid; t < 8 * NR * NW / 4; t += 256) {
    const int cap = t / (NR * NW / 4);
    const int rem = t - cap * (NR * NW / 4);
    const int r = rem >> 3, wq = rem & 7;
    const float4 v = *(const float4*)(Cp + cap * (NR * NW) + r * NW + wq * 4);
    *(float4*)&sS[cap][r * 36 + wq * 4] = v;
  }
  __syncthreads();
#pragma unroll
  for (int it = 0; it < 2; ++it) {
    const int capu = wv + it * 4;
    if (lane < NR) {
      float rn = 0.f;
#pragma unroll
      for (int k = 0; k < 8; ++k) {
        const float4 v = *(const float4*)&sS[capu][lane * 36 + k * 4];
        float l;
        l = leakyf(v.x); rn = fmaf(l, l, rn);
        l = leakyf(v.y); rn = fmaf(l, l, rn);
        l = leakyf(v.z); rn = fmaf(l, l, rn);
        l = leakyf(v.w); rn = fmaf(l, l, rn);
      }
      sInvR[capu][lane] = 20.f / (sqrtf(rn) + EPSF);
    }
  }
  __syncthreads();
  {
    const int capT = tid >> 5, wT = tid & 31;
    float s[NR], z[NR];
    float cn = 0.f;
#pragma unroll
    for (int j = 0; j < NR; ++j) {
      s[j] = sS[capT][j * 36 + wT];
      const float l = leakyf(s[j]);
      cn = fmaf(l, l, cn);
    }
    sInvC[capT][wT] = 20.f / (sqrtf(cn) + EPSF);
    float mz = -1e30f;
#pragma unroll
    for (int j = 0; j < NR; ++j) {
      z[j] = leakyf(s[j]) * sInvR[capT][j];
      mz = fmaxf(mz, z[j]);
    }
    float s1 = 0.f;
#pragma unroll
    for (int j = 0; j < NR; ++j) { z[j] = __expf(z[j] - mz); s1 += z[j]; }
    const float thr = s1 * (1.f / NR);
    float num = 0.f;
#pragma unroll
    for (int j = 0; j < NR; ++j) {
      z[j] = (z[j] > thr) ? z[j] : 0.f;
      num = fmaf(z[j], s[j], num);
    }
    const float* Gp = Gimg + (size_t)i * (NR * NR);
    float den2 = 0.f;
#pragma unroll
    for (int j = 0; j < NR; ++j) {
      float h = 0.5f * z[j] * Gp[j * NR + j];
#pragma unroll
      for (int j2 = j + 1; j2 < NR; ++j2) h = fmaf(z[j2], Gp[j * NR + j2], h);
      den2 = fmaf(z[j], h, den2);
    }
    const float val = num / (capn[(cg * 8 + capT) * NW + wT] * sqrtf(2.f * den2) + 1e-30f);
    float contrib = val * (1.f / NW);
#pragma unroll
    for (int d = 1; d < 32; d <<= 1) contrib += __shfl_xor(contrib, d, 64);
    if ((tid & 31) == 0) atomicAdd(&red[capT], contrib);
  }
  __syncthreads();
#pragma unroll
  for (int it = 0; it < 2; ++it) {
    const int capu = wv + it * 4;
    const int cglob = cg * 8 + capu;
    float contrib = 0.f;
    if (lane < NR) {
      float sr[NW], z[NW];
#pragma unroll
      for (int k = 0; k < 8; ++k)
        *(float4*)&sr[k * 4] = *(const float4*)&sS[capu][lane * 36 + k * 4];
      float mz = -1e30f;
#pragma unroll
      for (int w = 0; w < NW; ++w) {
        z[w] = leakyf(sr[w]) * sInvC[capu][w];
        mz = fmaxf(mz, z[w]);
      }
      float s1 = 0.f;
#pragma unroll
      for (int w = 0; w < NW; ++w) { z[w] = __expf(z[w] - mz); s1 += z[w]; }
      const float thr = s1 * (1.f / NW);
      float num = 0.f;
#pragma unroll
      for (int w = 0; w < NW; ++w) {
        z[w] = (z[w] > thr) ? z[w] : 0.f;
        num = fmaf(z[w], sr[w], num);
      }
      const float* Gp = Gcap + (size_t)cglob * (NW * NW);
      float den2 = 0.f;
#pragma unroll
      for (int w = 0; w < NW; ++w) {
        float h = 0.5f * z[w] * Gp[w * NW + w];
#pragma unroll
        for (int w2 = w + 1; w2 < NW; ++w2) h = fmaf(z[w2], Gp[w * NW + w2], h);
        den2 = fmaf(z[w], h, den2);
      }
      const float val = num / (imgn[i * NR + lane] * sqrtf(2.f * den2) + 1e-30f);
      contrib = val * (1.f / NR);
    }
#pragma unroll
    for (int d = 1; d < 64; d <<= 1) contrib += __shfl_xor(contrib, d, 64);
    if (lane == 0) atomicAdd(&red[capu], contrib);
  }
  __syncthreads();
  if (tid < 8) out[(size_t)i * 128 + cg * 8 + tid] = red[tid];
}

extern "C" void kernel_launch(void* const* d_in, const int* in_sizes, int n_in,
                              void* d_out, int out_size, void* d_ws, size_t ws_size,
                              hipStream_t stream) {
  (void)in_sizes; (void)n_in; (void)out_size; (void)ws_size;
  const float* images = (const float*)d_in[0];
  const float* captions = (const float*)d_in[1];
  float* out = (float*)d_out;

  char* wb = (char*)d_ws;
  _Float16* Ahf = (_Float16*)wb; wb += (size_t)4608 * 1024 * 2;
  _Float16* Alf = (_Float16*)wb; wb += (size_t)4608 * 1024 * 2;
  _Float16* Bhf = (_Float16*)wb; wb += (size_t)4096 * 1024 * 2;
  _Float16* Blf = (_Float16*)wb; wb += (size_t)4096 * 1024 * 2;
  float* Gimg = (float*)wb; wb += (size_t)128 * NR * NR * 4;
  float* Gcap = (float*)wb; wb += (size_t)128 * NW * NW * 4;
  float* imgn = (float*)wb; wb += (size_t)128 * NR * 4;
  float* capn = (float*)wb; wb += (size_t)128 * NW * 4;
  float* C = (float*)wb;

  prep_kernel<<<256, 256, 0, stream>>>(images, captions, Gimg, Gcap, imgn, capn,
                                       Ahf, Alf, Bhf, Blf);
  mfma_gemm_kernel<<<1152, 256, 0, stream>>>(Ahf, Alf, Bhf, Blf, C);
  fused_attn_kernel<<<dim3(128, 16), 256, 0, stream>>>(C, Gimg, Gcap, imgn, capn, out);
}